// Round 1
// baseline (189.989 us; speedup 1.0000x reference)
//
#include <hip/hip_runtime.h>
#include <math.h>

// OptNet: the fc1+ReLU over x/W1/b1 is dead code in the reference (result
// unused). The live computation is a 10x10 QP with one inequality:
//   Q = tril(L) tril(L)^T + eps*I
//   z_unc = Q^{-1}(-p),  Qi_g = Q^{-1} g
//   lam = max(g.z_unc - h, 0) / (g.Qi_g),  z = z_unc - lam*Qi_g
//   out = log_softmax(z)
// ~1 kFLOP total -> one thread, fp64 internally for accuracy headroom.

#define NC 10
#define QP_EPS 1e-4

__global__ void optnet_qp_kernel(const float* __restrict__ L,
                                 const float* __restrict__ p,
                                 const float* __restrict__ G,
                                 const float* __restrict__ z0,
                                 const float* __restrict__ s0,
                                 float* __restrict__ out) {
    if (threadIdx.x != 0 || blockIdx.x != 0) return;

    // Build Q = tril(L) tril(L)^T + eps*I directly into C (lower part used).
    double C[NC][NC];
    for (int i = 0; i < NC; ++i) {
        for (int j = 0; j <= i; ++j) {
            double s = 0.0;
            // sum_{k<=j} Lm[i][k]*Lm[j][k]  (j<=i so min(i,j)=j)
            for (int k = 0; k <= j; ++k)
                s += (double)L[i * NC + k] * (double)L[j * NC + k];
            if (i == j) s += QP_EPS;
            C[i][j] = s;
        }
    }

    double g[NC], nb[NC];
    for (int i = 0; i < NC; ++i) {
        g[i] = (double)G[i];
        nb[i] = -(double)p[i];
    }
    double h = (double)s0[0];
    for (int k = 0; k < NC; ++k) h += g[k] * (double)z0[k];

    // In-place Cholesky: C (lower) := chol factor of Q.
    for (int j = 0; j < NC; ++j) {
        double d = C[j][j];
        for (int k = 0; k < j; ++k) d -= C[j][k] * C[j][k];
        d = sqrt(d);
        C[j][j] = d;
        double inv_d = 1.0 / d;
        for (int i = j + 1; i < NC; ++i) {
            double s = C[i][j];
            for (int k = 0; k < j; ++k) s -= C[i][k] * C[j][k];
            C[i][j] = s * inv_d;
        }
    }

    // Two solves with the same factor: zu = Q^{-1}(-p), qg = Q^{-1} g.
    double zu[NC], qg[NC];
    {
        double y1[NC], y2[NC];
        for (int i = 0; i < NC; ++i) {
            double s1 = nb[i], s2 = g[i];
            for (int k = 0; k < i; ++k) {
                s1 -= C[i][k] * y1[k];
                s2 -= C[i][k] * y2[k];
            }
            double inv = 1.0 / C[i][i];
            y1[i] = s1 * inv;
            y2[i] = s2 * inv;
        }
        for (int i = NC - 1; i >= 0; --i) {
            double s1 = y1[i], s2 = y2[i];
            for (int k = i + 1; k < NC; ++k) {
                s1 -= C[k][i] * zu[k];
                s2 -= C[k][i] * qg[k];
            }
            double inv = 1.0 / C[i][i];
            zu[i] = s1 * inv;
            qg[i] = s2 * inv;
        }
    }

    double viol = -h, denom = 0.0;
    for (int i = 0; i < NC; ++i) {
        viol += g[i] * zu[i];
        denom += g[i] * qg[i];
    }
    double lam = (viol > 0.0) ? viol / denom : 0.0;

    double z[NC];
    for (int i = 0; i < NC; ++i) z[i] = zu[i] - lam * qg[i];

    // log_softmax
    double mx = z[0];
    for (int i = 1; i < NC; ++i) mx = (z[i] > mx) ? z[i] : mx;
    double se = 0.0;
    for (int i = 0; i < NC; ++i) se += exp(z[i] - mx);
    double lse = log(se);
    for (int i = 0; i < NC; ++i) out[i] = (float)(z[i] - mx - lse);
}

extern "C" void kernel_launch(void* const* d_in, const int* in_sizes, int n_in,
                              void* d_out, int out_size, void* d_ws, size_t ws_size,
                              hipStream_t stream) {
    // Input order: x, W1, b1, L, p, G, z0, s0 — x/W1/b1 are dead code.
    const float* L  = (const float*)d_in[3];
    const float* p  = (const float*)d_in[4];
    const float* G  = (const float*)d_in[5];
    const float* z0 = (const float*)d_in[6];
    const float* s0 = (const float*)d_in[7];
    float* out = (float*)d_out;

    optnet_qp_kernel<<<1, 64, 0, stream>>>(L, p, G, z0, s0, out);
}

// Round 2
// 176.390 us; speedup vs baseline: 1.0771x; 1.0771x over previous
//
#include <hip/hip_runtime.h>
#include <math.h>

// OptNet: fc1+ReLU over x/W1/b1 is dead code (result unused in the reference).
// Live computation: 10x10 single-inequality QP + log_softmax (~1 kFLOP).
//
// R1 lesson: runtime-indexed local arrays put the 100-double workspace in
// scratch -> ~190us of serialized spill latency. Fix: fully unroll every loop
// (NC=10 compile-time) so all indexing is static and the whole working set
// (~300 VGPRs: tril(L) 55 + C 55 doubles + vectors) stays in registers
// (no spill through ~450 VGPRs, occupancy irrelevant at 1 wave).

#define NC 10
#define QP_EPS 1e-4

__launch_bounds__(64, 1)
__global__ void optnet_qp_kernel(const float* __restrict__ Lp,
                                 const float* __restrict__ pp,
                                 const float* __restrict__ Gp,
                                 const float* __restrict__ z0p,
                                 const float* __restrict__ s0p,
                                 float* __restrict__ out) {
    if (threadIdx.x != 0) return;

    // ---- Load lower triangle of L into registers (static indexing) ----
    double Lr[NC][NC];
#pragma unroll
    for (int i = 0; i < NC; ++i) {
#pragma unroll
        for (int j = 0; j <= i; ++j) {
            Lr[i][j] = (double)Lp[i * NC + j];
        }
    }

    double g[NC], nb[NC];
#pragma unroll
    for (int i = 0; i < NC; ++i) {
        g[i]  = (double)Gp[i];
        nb[i] = -(double)pp[i];
    }
    double h = (double)s0p[0];
#pragma unroll
    for (int k = 0; k < NC; ++k) h += g[k] * (double)z0p[k];

    // ---- C = tril(L) tril(L)^T + eps*I (lower triangle only) ----
    double C[NC][NC];
#pragma unroll
    for (int i = 0; i < NC; ++i) {
#pragma unroll
        for (int j = 0; j <= i; ++j) {
            double s = (i == j) ? (double)QP_EPS : 0.0;
#pragma unroll
            for (int k = 0; k <= j; ++k)
                s += Lr[i][k] * Lr[j][k];
            C[i][j] = s;
        }
    }

    // ---- In-place Cholesky: C := chol(Q), lower ----
#pragma unroll
    for (int j = 0; j < NC; ++j) {
        double d = C[j][j];
#pragma unroll
        for (int k = 0; k < j; ++k) d -= C[j][k] * C[j][k];
        d = sqrt(d);
        C[j][j] = d;
        double inv_d = 1.0 / d;
#pragma unroll
        for (int i = j + 1; i < NC; ++i) {
            double s = C[i][j];
#pragma unroll
            for (int k = 0; k < j; ++k) s -= C[i][k] * C[j][k];
            C[i][j] = s * inv_d;
        }
    }

    // ---- Two solves with the same factor: zu = Q^{-1}(-p), qg = Q^{-1} g ----
    double y1[NC], y2[NC], zu[NC], qg[NC];
#pragma unroll
    for (int i = 0; i < NC; ++i) {
        double s1 = nb[i], s2 = g[i];
#pragma unroll
        for (int k = 0; k < i; ++k) {
            s1 -= C[i][k] * y1[k];
            s2 -= C[i][k] * y2[k];
        }
        double inv = 1.0 / C[i][i];
        y1[i] = s1 * inv;
        y2[i] = s2 * inv;
    }
#pragma unroll
    for (int i = NC - 1; i >= 0; --i) {
        double s1 = y1[i], s2 = y2[i];
#pragma unroll
        for (int k = i + 1; k < NC; ++k) {
            s1 -= C[k][i] * zu[k];
            s2 -= C[k][i] * qg[k];
        }
        double inv = 1.0 / C[i][i];
        zu[i] = s1 * inv;
        qg[i] = s2 * inv;
    }

    // ---- KKT clip ----
    double viol = -h, denom = 0.0;
#pragma unroll
    for (int i = 0; i < NC; ++i) {
        viol  += g[i] * zu[i];
        denom += g[i] * qg[i];
    }
    double lam = (viol > 0.0) ? viol / denom : 0.0;

    // ---- log_softmax in fp32 (threshold 0.46; expf/logf are plenty) ----
    float z[NC];
#pragma unroll
    for (int i = 0; i < NC; ++i) z[i] = (float)(zu[i] - lam * qg[i]);

    float mx = z[0];
#pragma unroll
    for (int i = 1; i < NC; ++i) mx = fmaxf(mx, z[i]);
    float se = 0.0f;
#pragma unroll
    for (int i = 0; i < NC; ++i) se += __expf(z[i] - mx);
    float lse = __logf(se);
#pragma unroll
    for (int i = 0; i < NC; ++i) out[i] = z[i] - mx - lse;
}

extern "C" void kernel_launch(void* const* d_in, const int* in_sizes, int n_in,
                              void* d_out, int out_size, void* d_ws, size_t ws_size,
                              hipStream_t stream) {
    // Input order: x, W1, b1, L, p, G, z0, s0 — x/W1/b1 are dead code.
    const float* L  = (const float*)d_in[3];
    const float* p  = (const float*)d_in[4];
    const float* G  = (const float*)d_in[5];
    const float* z0 = (const float*)d_in[6];
    const float* s0 = (const float*)d_in[7];
    float* out = (float*)d_out;

    optnet_qp_kernel<<<1, 64, 0, stream>>>(L, p, G, z0, s0, out);
}